// Round 1
// baseline (569.670 us; speedup 1.0000x reference)
//
#include <hip/hip_runtime.h>
#include <hip/hip_bf16.h>

// Problem constants (fixed by setup_inputs)
#define HH 240
#define WW 320
#define PP (HH * WW)          // 76800 pixels
#define CC 22                 // classes
#define QW 20                 // query grid width  (320/16)
#define QH 15                 // query grid height (240/16)
#define QQ (QW * QH)          // 300 queries
#define EPSF 1e-6f
#define INLIER_TF 0.9f

// ---------------- kernel 0: zero the label histogram ----------------
__global__ void hv_init(int* hist) {
    int t = threadIdx.x;
    if (t < CC) hist[t] = 0;
}

// ---------------- kernel 1: per-pixel prep ----------------
// ux,uy = normalized (dx,dy) of the label-selected vertex channel; dz raw.
// Also builds the per-class pixel-count histogram.
__global__ void hv_prep(const int* __restrict__ label,
                        const float* __restrict__ vp,   // (3C, H, W) planes
                        float* __restrict__ ux, float* __restrict__ uy,
                        float* __restrict__ dz, int* __restrict__ hist) {
    int p = blockIdx.x * blockDim.x + threadIdx.x;
    if (p >= PP) return;
    int lab = label[p];
    const float* base = vp + (size_t)(lab * 3) * PP + p;
    float dx = base[0];
    float dy = base[PP];
    float dzv = base[2 * PP];
    float dn = sqrtf(dx * dx + dy * dy) + EPSF;
    ux[p] = dx / dn;
    uy[p] = dy / dn;
    dz[p] = dzv;
    atomicAdd(&hist[lab], 1);
}

// ---------------- kernel 2: voting ----------------
// One block per query point. LDS per-class inlier counters.
__global__ void hv_vote(const int* __restrict__ label,
                        const float* __restrict__ ux,
                        const float* __restrict__ uy,
                        int* __restrict__ acc /* (Q, C) */) {
    __shared__ int accl[CC];
    int q = blockIdx.x;
    int tid = threadIdx.x;
    if (tid < CC) accl[tid] = 0;
    __syncthreads();

    float qx = (float)((q % QW) * 16);
    float qy = (float)((q / QW) * 16);

    for (int p = tid; p < PP; p += blockDim.x) {
        int lab = label[p];
        if (lab > 0) {
            float px = (float)(p % WW);
            float py = (float)(p / WW);
            float cx = qx - px;
            float cy = qy - py;
            float cn = sqrtf(cx * cx + cy * cy) + EPSF;
            float cosv = (cx * ux[p] + cy * uy[p]) / cn;
            if (cosv > INLIER_TF) atomicAdd(&accl[lab], 1);
        }
    }
    __syncthreads();
    if (tid < CC) acc[q * CC + tid] = accl[tid];
}

// ---------------- kernel 3: per-class argmax over queries ----------------
// jnp.argmax semantics: first occurrence of the maximum.
__global__ void hv_argmax(const int* __restrict__ acc,
                          int* __restrict__ best_q, int* __restrict__ best_v) {
    int c = threadIdx.x;
    if (c >= CC) return;
    int bv = acc[c];   // q = 0
    int bq = 0;
    for (int q = 1; q < QQ; ++q) {
        int v = acc[q * CC + c];
        if (v > bv) { bv = v; bq = q; }
    }
    best_q[c] = bq;
    best_v[c] = bv;
}

// ---------------- kernel 4: per-class depth gather + epilogue ----------------
// One block per class: scan pixels of this class against its best query,
// reduce (cnt, sum dz), then thread 0 writes the 14 output columns.
__global__ void hv_final(const int* __restrict__ label,
                         const float* __restrict__ ux,
                         const float* __restrict__ uy,
                         const float* __restrict__ dz,
                         const int* __restrict__ hist,
                         const int* __restrict__ best_q,
                         const int* __restrict__ best_v,
                         const float* __restrict__ extents,
                         const float* __restrict__ poses,
                         const float* __restrict__ meta,
                         float* __restrict__ out /* (C, 14) */) {
    __shared__ float s_z[256];
    __shared__ int   s_c[256];
    int c = blockIdx.x;
    int tid = threadIdx.x;

    int bq = best_q[c];
    float qx = (float)((bq % QW) * 16);
    float qy = (float)((bq / QW) * 16);

    float zsum = 0.0f;
    int cnt = 0;
    if (c > 0) {  // class 0 pixels are never fg-inliers
        for (int p = tid; p < PP; p += blockDim.x) {
            if (label[p] == c) {
                float px = (float)(p % WW);
                float py = (float)(p / WW);
                float cx = qx - px;
                float cy = qy - py;
                float cn = sqrtf(cx * cx + cy * cy) + EPSF;
                float cosv = (cx * ux[p] + cy * uy[p]) / cn;
                if (cosv > INLIER_TF) { cnt += 1; zsum += dz[p]; }
            }
        }
    }
    s_z[tid] = zsum;
    s_c[tid] = cnt;
    __syncthreads();
    for (int s = 128; s > 0; s >>= 1) {
        if (tid < s) { s_z[tid] += s_z[tid + s]; s_c[tid] += s_c[tid + s]; }
        __syncthreads();
    }

    if (tid == 0) {
        float bv = (float)best_v[c];
        float cc = (float)hist[c];
        float z = s_z[0] / ((float)s_c[0] + EPSF);

        float fx = meta[0] + EPSF;
        float fy = meta[4] + EPSF;
        float ppx = meta[2];
        float ppy = meta[5];

        float e0 = extents[c * 3 + 0];
        float e1 = extents[c * 3 + 1];
        float e2 = extents[c * 3 + 2];
        float half = 0.5f * sqrtf(e0 * e0 + e1 * e1 + e2 * e2);

        float zsafe = (fabsf(z) > EPSF) ? z : EPSF;
        float r = fx * half / zsafe;

        bool valid = (bv >= 50.0f) && (cc >= 500.0f) &&
                     (bv / (cc + EPSF) >= 0.02f);
        float score = valid ? bv : 0.0f;

        float* o = out + c * 14;
        o[0] = 0.0f;
        o[1] = (float)c;
        o[2] = qx - r;
        o[3] = qy - r;
        o[4] = qx + r;
        o[5] = qy + r;
        o[6] = score;
        o[7]  = poses[c * 13 + 6];
        o[8]  = poses[c * 13 + 7];
        o[9]  = poses[c * 13 + 8];
        o[10] = poses[c * 13 + 9];
        o[11] = (qx - ppx) * z / fx;
        o[12] = (qy - ppy) * z / fy;
        o[13] = z;
    }
}

extern "C" void kernel_launch(void* const* d_in, const int* in_sizes, int n_in,
                              void* d_out, int out_size, void* d_ws, size_t ws_size,
                              hipStream_t stream) {
    const int*   label   = (const int*)d_in[0];
    const float* vp      = (const float*)d_in[1];
    const float* extents = (const float*)d_in[2];
    const float* poses   = (const float*)d_in[3];
    const float* meta    = (const float*)d_in[4];
    float* out = (float*)d_out;

    // workspace layout (floats/ints, all 4-byte)
    float* ws   = (float*)d_ws;
    float* ux   = ws;
    float* uy   = ws + PP;
    float* dz   = ws + 2 * PP;
    int*   acc  = (int*)(ws + 3 * PP);   // Q*C
    int*   hist = acc + QQ * CC;         // C
    int*   bq   = hist + CC;             // C
    int*   bv   = bq + CC;               // C

    hv_init<<<1, 64, 0, stream>>>(hist);
    hv_prep<<<(PP + 255) / 256, 256, 0, stream>>>(label, vp, ux, uy, dz, hist);
    hv_vote<<<QQ, 256, 0, stream>>>(label, ux, uy, acc);
    hv_argmax<<<1, 64, 0, stream>>>(acc, bq, bv);
    hv_final<<<CC, 256, 0, stream>>>(label, ux, uy, dz, hist, bq, bv,
                                     extents, poses, meta, out);
}

// Round 2
// 136.395 us; speedup vs baseline: 4.1766x; 4.1766x over previous
//
#include <hip/hip_runtime.h>
#include <hip/hip_bf16.h>

// Problem constants (fixed by setup_inputs)
#define HH 240
#define WW 320
#define PP (HH * WW)          // 76800 pixels
#define CC 22                 // classes
#define QW 20                 // query grid width  (320/16)
#define QH 15                 // query grid height (240/16)
#define QQ (QW * QH)          // 300 queries
#define SEG 16                // pixel segments for the vote kernel
#define EPSF 1e-6f
#define INLIER_TF 0.9f

// ---------------- kernel 1: per-pixel prep ----------------
// ux,uy = normalized (dx,dy) of the label-selected vertex channel; dz raw.
// Also builds the per-class pixel-count histogram (int atomics).
__global__ void hv_prep(const int* __restrict__ label,
                        const float* __restrict__ vp,   // (3C, H, W) planes
                        float* __restrict__ ux, float* __restrict__ uy,
                        float* __restrict__ dz, int* __restrict__ hist) {
    __shared__ int s_hist[CC];
    int tid = threadIdx.x;
    if (tid < CC) s_hist[tid] = 0;
    __syncthreads();

    int p = blockIdx.x * blockDim.x + tid;
    if (p < PP) {
        int lab = label[p];
        const float* base = vp + (size_t)(lab * 3) * PP + p;
        float dx = base[0];
        float dy = base[PP];
        float dzv = base[2 * PP];
        float dn = sqrtf(dx * dx + dy * dy) + EPSF;
        ux[p] = dx / dn;
        uy[p] = dy / dn;
        dz[p] = dzv;
        atomicAdd(&s_hist[lab], 1);
    }
    __syncthreads();
    if (tid < CC && s_hist[tid]) atomicAdd(&hist[tid], s_hist[tid]);
}

// ---------------- kernel 2: voting ----------------
// Grid (QQ, SEG): block = one query x one pixel segment.
// LDS per-class counters, one global int atomic per class per block.
__global__ void hv_vote(const int* __restrict__ label,
                        const float* __restrict__ ux,
                        const float* __restrict__ uy,
                        int* __restrict__ acc /* (Q, C) */) {
    __shared__ int accl[CC];
    int q = blockIdx.x;
    int seg = blockIdx.y;
    int tid = threadIdx.x;
    if (tid < CC) accl[tid] = 0;
    __syncthreads();

    float qx = (float)((q % QW) * 16);
    float qy = (float)((q / QW) * 16);

    const int chunk = PP / SEG;           // 4800
    int p0 = seg * chunk;
    int p1 = p0 + chunk;
    for (int p = p0 + tid; p < p1; p += blockDim.x) {
        int lab = label[p];
        if (lab > 0) {
            float px = (float)(p % WW);
            float py = (float)(p / WW);
            float cx = qx - px;
            float cy = qy - py;
            float cn = sqrtf(cx * cx + cy * cy) + EPSF;
            float cosv = (cx * ux[p] + cy * uy[p]) / cn;
            if (cosv > INLIER_TF) atomicAdd(&accl[lab], 1);
        }
    }
    __syncthreads();
    if (tid < CC && accl[tid]) atomicAdd(&acc[q * CC + tid], accl[tid]);
}

// ---------------- kernel 3: per-class argmax over queries ----------------
// One wave per class; jnp.argmax semantics (first occurrence of max).
__global__ void hv_argmax(const int* __restrict__ acc,
                          int* __restrict__ best_q, int* __restrict__ best_v) {
    int c = blockIdx.x;
    int lane = threadIdx.x;      // 0..63
    int bv = -1, bq = QQ;
    for (int q = lane; q < QQ; q += 64) {
        int v = acc[q * CC + c];
        if (v > bv) { bv = v; bq = q; }   // increasing q -> keeps first max
    }
    for (int off = 32; off > 0; off >>= 1) {
        int ov = __shfl_down(bv, off);
        int oq = __shfl_down(bq, off);
        if (ov > bv || (ov == bv && oq < bq)) { bv = ov; bq = oq; }
    }
    if (lane == 0) { best_q[c] = bq; best_v[c] = bv; }
}

// ---------------- kernel 4: pixel-parallel depth gather ----------------
// Each pixel tests against its own class's best query; LDS-reduced
// (cnt, sum dz) per class, then one global atomic per class per block.
__global__ void hv_gather(const int* __restrict__ label,
                          const float* __restrict__ ux,
                          const float* __restrict__ uy,
                          const float* __restrict__ dz,
                          const int* __restrict__ best_q,
                          int* __restrict__ cnt, float* __restrict__ zsum) {
    __shared__ float s_qx[CC], s_qy[CC];
    __shared__ int s_cnt[CC];
    __shared__ float s_z[CC];
    int tid = threadIdx.x;
    if (tid < CC) {
        int bq = best_q[tid];
        s_qx[tid] = (float)((bq % QW) * 16);
        s_qy[tid] = (float)((bq / QW) * 16);
        s_cnt[tid] = 0;
        s_z[tid] = 0.0f;
    }
    __syncthreads();

    int p = blockIdx.x * blockDim.x + tid;
    if (p < PP) {
        int lab = label[p];
        if (lab > 0) {
            float px = (float)(p % WW);
            float py = (float)(p / WW);
            float cx = s_qx[lab] - px;
            float cy = s_qy[lab] - py;
            float cn = sqrtf(cx * cx + cy * cy) + EPSF;
            float cosv = (cx * ux[p] + cy * uy[p]) / cn;
            if (cosv > INLIER_TF) {
                atomicAdd(&s_cnt[lab], 1);
                atomicAdd(&s_z[lab], dz[p]);
            }
        }
    }
    __syncthreads();
    if (tid < CC && s_cnt[tid]) {
        atomicAdd(&cnt[tid], s_cnt[tid]);
        atomicAdd(&zsum[tid], s_z[tid]);
    }
}

// ---------------- kernel 5: epilogue ----------------
__global__ void hv_epilogue(const int* __restrict__ hist,
                            const int* __restrict__ best_q,
                            const int* __restrict__ best_v,
                            const int* __restrict__ cnt,
                            const float* __restrict__ zsum,
                            const float* __restrict__ extents,
                            const float* __restrict__ poses,
                            const float* __restrict__ meta,
                            float* __restrict__ out /* (C, 14) */) {
    int c = threadIdx.x;
    if (c >= CC) return;

    int bq = best_q[c];
    float qx = (float)((bq % QW) * 16);
    float qy = (float)((bq / QW) * 16);

    float bv = (float)best_v[c];
    float cc = (float)hist[c];
    float z = zsum[c] / ((float)cnt[c] + EPSF);

    float fx = meta[0] + EPSF;
    float fy = meta[4] + EPSF;
    float ppx = meta[2];
    float ppy = meta[5];

    float e0 = extents[c * 3 + 0];
    float e1 = extents[c * 3 + 1];
    float e2 = extents[c * 3 + 2];
    float half = 0.5f * sqrtf(e0 * e0 + e1 * e1 + e2 * e2);

    float zsafe = (fabsf(z) > EPSF) ? z : EPSF;
    float r = fx * half / zsafe;

    bool valid = (bv >= 50.0f) && (cc >= 500.0f) &&
                 (bv / (cc + EPSF) >= 0.02f);
    float score = valid ? bv : 0.0f;

    float* o = out + c * 14;
    o[0] = 0.0f;
    o[1] = (float)c;
    o[2] = qx - r;
    o[3] = qy - r;
    o[4] = qx + r;
    o[5] = qy + r;
    o[6] = score;
    o[7]  = poses[c * 13 + 6];
    o[8]  = poses[c * 13 + 7];
    o[9]  = poses[c * 13 + 8];
    o[10] = poses[c * 13 + 9];
    o[11] = (qx - ppx) * z / fx;
    o[12] = (qy - ppy) * z / fy;
    o[13] = z;
}

extern "C" void kernel_launch(void* const* d_in, const int* in_sizes, int n_in,
                              void* d_out, int out_size, void* d_ws, size_t ws_size,
                              hipStream_t stream) {
    const int*   label   = (const int*)d_in[0];
    const float* vp      = (const float*)d_in[1];
    const float* extents = (const float*)d_in[2];
    const float* poses   = (const float*)d_in[3];
    const float* meta    = (const float*)d_in[4];
    float* out = (float*)d_out;

    // workspace layout (4-byte elements)
    float* ws   = (float*)d_ws;
    float* ux   = ws;
    float* uy   = ws + PP;
    float* dz   = ws + 2 * PP;
    // zero-initialized region (contiguous): acc, hist, cnt, zsum
    int*   acc  = (int*)(ws + 3 * PP);     // QQ*CC = 6600
    int*   hist = acc + QQ * CC;           // CC
    int*   cnt  = hist + CC;               // CC
    float* zsum = (float*)(cnt + CC);      // CC
    int*   bq   = (int*)(zsum + CC);       // CC
    int*   bv   = bq + CC;                 // CC

    hipMemsetAsync(acc, 0, (QQ * CC + 3 * CC) * sizeof(int), stream);
    hv_prep<<<(PP + 255) / 256, 256, 0, stream>>>(label, vp, ux, uy, dz, hist);
    hv_vote<<<dim3(QQ, SEG), 256, 0, stream>>>(label, ux, uy, acc);
    hv_argmax<<<CC, 64, 0, stream>>>(acc, bq, bv);
    hv_gather<<<(PP + 255) / 256, 256, 0, stream>>>(label, ux, uy, dz, bq, cnt, zsum);
    hv_epilogue<<<1, 64, 0, stream>>>(hist, bq, bv, cnt, zsum,
                                      extents, poses, meta, out);
}

// Round 3
// 128.235 us; speedup vs baseline: 4.4424x; 1.0636x over previous
//
#include <hip/hip_runtime.h>
#include <hip/hip_bf16.h>

// Problem constants (fixed by setup_inputs)
#define HH 240
#define WW 320
#define PP (HH * WW)          // 76800 pixels
#define CC 22                 // classes
#define QW 20                 // query grid width  (320/16)
#define QH 15                 // query grid height (240/16)
#define QQ (QW * QH)          // 300 queries
#define QG 5                  // query groups (vote kernel grid.y)
#define QROWS 3               // query rows per group
#define QPG (QROWS * QW)      // 60 queries per group
#define PB (PP / 256)         // 300 pixel blocks
#define EPSF 1e-6f
#define INLIER_TF 0.9f

// ---------------- kernel 1: per-pixel prep + zero-init ----------------
// ux,uy = normalized (dx,dy) of the label-selected vertex channel; dz raw.
// Also zeroes acc / hist / cnt / zsum / ctr (ws is poisoned each call).
__global__ void hv_prep(const int* __restrict__ label,
                        const float* __restrict__ vp,   // (3C, H, W) planes
                        float* __restrict__ ux, float* __restrict__ uy,
                        float* __restrict__ dz,
                        int* __restrict__ acc, int* __restrict__ hist,
                        int* __restrict__ cnt, float* __restrict__ zsum,
                        unsigned* __restrict__ ctr) {
    int tid = threadIdx.x;
    int b = blockIdx.x;
    // zero the (Q,C) accumulator: block b owns entries [b*22, b*22+22)
    if (tid < CC) acc[b * CC + tid] = 0;
    if (b == 0 && tid < CC) {
        hist[tid] = 0; cnt[tid] = 0; zsum[tid] = 0.0f;
        if (tid == 0) *ctr = 0u;
    }

    int p = b * blockDim.x + tid;
    if (p < PP) {
        int lab = label[p];
        const float* base = vp + (size_t)(lab * 3) * PP + p;
        float dx = base[0];
        float dy = base[PP];
        float dzv = base[2 * PP];
        float dn = sqrtf(dx * dx + dy * dy) + EPSF;
        ux[p] = dx / dn;
        uy[p] = dy / dn;
        dz[p] = dzv;
    }
}

// ---------------- kernel 2: voting (pixel-register form) ----------------
// Grid (PB, QG): block = 256 pixels x 60 queries (3 query rows).
// Pixel state lives in registers; LDS (60,22) counters; one global int
// atomic per nonzero entry. g==0 slice also builds the label histogram.
__global__ void hv_vote(const int* __restrict__ label,
                        const float* __restrict__ ux,
                        const float* __restrict__ uy,
                        int* __restrict__ acc /* (Q, C) */,
                        int* __restrict__ hist) {
    __shared__ int accl[QPG * CC];   // 1320 ints = 5.28 KB
    __shared__ int s_hist[CC];
    int tid = threadIdx.x;
    int pb = blockIdx.x;
    int g = blockIdx.y;

    for (int i = tid; i < QPG * CC; i += 256) accl[i] = 0;
    if (g == 0 && tid < CC) s_hist[tid] = 0;
    __syncthreads();

    int p = pb * 256 + tid;          // always < PP (grid sized exactly)
    int lab = label[p];
    float uxv = ux[p];
    float uyv = uy[p];
    float px = (float)(p % WW);
    float py = (float)(p / WW);

    if (g == 0) atomicAdd(&s_hist[lab], 1);

    if (lab > 0) {
        for (int ry = 0; ry < QROWS; ++ry) {
            float qy = (float)((g * QROWS + ry) * 16);
            float cy = qy - py;                       // exact (small ints)
            for (int rx = 0; rx < QW; ++rx) {
                float qx = (float)(rx * 16);
                float cx = qx - px;                   // exact (small ints)
                float cn = sqrtf(cx * cx + cy * cy) + EPSF;
                float cosv = (cx * uxv + cy * uyv) / cn;
                if (cosv > INLIER_TF)
                    atomicAdd(&accl[(ry * QW + rx) * CC + lab], 1);
            }
        }
    }
    __syncthreads();

    int base = g * QPG * CC;
    for (int i = tid; i < QPG * CC; i += 256) {
        int v = accl[i];
        if (v) atomicAdd(&acc[base + i], v);
    }
    if (g == 0 && tid < CC) {
        int h = s_hist[tid];
        if (h) atomicAdd(&hist[tid], h);
    }
}

// ---------------- kernel 3: argmax + depth gather + epilogue ----------------
// 300 blocks. Each block recomputes the per-class argmax from L2-resident
// acc (first-occurrence semantics), reduces (cnt, sum dz) for its 256
// pixels, and the LAST block (atomic counter) writes the (22,14) output.
__global__ void hv_gather(const int* __restrict__ label,
                          const float* __restrict__ ux,
                          const float* __restrict__ uy,
                          const float* __restrict__ dz,
                          const int* __restrict__ acc,
                          const int* __restrict__ hist,
                          int* __restrict__ cnt, float* __restrict__ zsum,
                          unsigned* __restrict__ ctr,
                          const float* __restrict__ extents,
                          const float* __restrict__ poses,
                          const float* __restrict__ meta,
                          float* __restrict__ out /* (C, 14) */) {
    __shared__ int s_bv[11 * CC], s_bq[11 * CC];
    __shared__ float s_qx[CC], s_qy[CC];
    __shared__ int s_cnt[CC];
    __shared__ float s_z[CC];
    __shared__ int s_last;
    int tid = threadIdx.x;

    // --- per-class argmax over 300 queries, chunked 11 x 28 ---
    if (tid < 11 * CC) {
        int c = tid % CC;
        int chunk = tid / CC;
        int qa = chunk * 28;
        int qb = (qa + 28 < QQ) ? qa + 28 : QQ;
        int bv = -1, bq = 0;
        for (int q = qa; q < qb; ++q) {
            int v = acc[q * CC + c];
            if (v > bv) { bv = v; bq = q; }    // ascending q -> first max
        }
        s_bv[tid] = bv;
        s_bq[tid] = bq;
    }
    if (tid < CC) { s_cnt[tid] = 0; s_z[tid] = 0.0f; }
    __syncthreads();
    if (tid < CC) {
        int bv = s_bv[tid], bq = s_bq[tid];    // chunk 0 (lowest q)
        for (int ch = 1; ch < 11; ++ch) {
            int v = s_bv[ch * CC + tid];
            if (v > bv) { bv = v; bq = s_bq[ch * CC + tid]; }  // strict > keeps earlier
        }
        s_bv[tid] = bv;                        // final, in chunk-0 row
        s_qx[tid] = (float)((bq % QW) * 16);
        s_qy[tid] = (float)((bq / QW) * 16);
    }
    __syncthreads();

    // --- per-pixel inlier test against own class's best query ---
    int p = blockIdx.x * 256 + tid;
    int lab = label[p];
    if (lab > 0) {
        float px = (float)(p % WW);
        float py = (float)(p / WW);
        float cx = s_qx[lab] - px;
        float cy = s_qy[lab] - py;
        float cn = sqrtf(cx * cx + cy * cy) + EPSF;
        float cosv = (cx * ux[p] + cy * uy[p]) / cn;
        if (cosv > INLIER_TF) {
            atomicAdd(&s_cnt[lab], 1);
            atomicAdd(&s_z[lab], dz[p]);
        }
    }
    __syncthreads();
    if (tid < CC && s_cnt[tid]) {
        atomicAdd(&cnt[tid], s_cnt[tid]);
        atomicAdd(&zsum[tid], s_z[tid]);
    }

    // --- last block writes the epilogue ---
    __threadfence();
    if (tid == 0) {
        unsigned done = atomicAdd(ctr, 1u);
        s_last = (done == gridDim.x - 1) ? 1 : 0;
    }
    __syncthreads();
    if (s_last && tid < CC) {
        int c = tid;
        int cv = atomicAdd(&cnt[c], 0);          // coherent read
        float zs = atomicAdd(&zsum[c], 0.0f);    // coherent read
        float z = zs / ((float)cv + EPSF);

        float bv = (float)s_bv[c];
        float cc = (float)hist[c];               // prior dispatch: plain load ok
        float bx = s_qx[c], by = s_qy[c];

        float fx = meta[0] + EPSF;
        float fy = meta[4] + EPSF;
        float ppx = meta[2];
        float ppy = meta[5];

        float e0 = extents[c * 3 + 0];
        float e1 = extents[c * 3 + 1];
        float e2 = extents[c * 3 + 2];
        float half = 0.5f * sqrtf(e0 * e0 + e1 * e1 + e2 * e2);

        float zsafe = (fabsf(z) > EPSF) ? z : EPSF;
        float r = fx * half / zsafe;

        bool valid = (bv >= 50.0f) && (cc >= 500.0f) &&
                     (bv / (cc + EPSF) >= 0.02f);
        float score = valid ? bv : 0.0f;

        float* o = out + c * 14;
        o[0] = 0.0f;
        o[1] = (float)c;
        o[2] = bx - r;
        o[3] = by - r;
        o[4] = bx + r;
        o[5] = by + r;
        o[6] = score;
        o[7]  = poses[c * 13 + 6];
        o[8]  = poses[c * 13 + 7];
        o[9]  = poses[c * 13 + 8];
        o[10] = poses[c * 13 + 9];
        o[11] = (bx - ppx) * z / fx;
        o[12] = (by - ppy) * z / fy;
        o[13] = z;
    }
}

extern "C" void kernel_launch(void* const* d_in, const int* in_sizes, int n_in,
                              void* d_out, int out_size, void* d_ws, size_t ws_size,
                              hipStream_t stream) {
    const int*   label   = (const int*)d_in[0];
    const float* vp      = (const float*)d_in[1];
    const float* extents = (const float*)d_in[2];
    const float* poses   = (const float*)d_in[3];
    const float* meta    = (const float*)d_in[4];
    float* out = (float*)d_out;

    // workspace layout (4-byte elements)
    float* ws   = (float*)d_ws;
    float* ux   = ws;
    float* uy   = ws + PP;
    float* dz   = ws + 2 * PP;
    int*   acc  = (int*)(ws + 3 * PP);     // QQ*CC = 6600
    int*   hist = acc + QQ * CC;           // CC
    int*   cnt  = hist + CC;               // CC
    float* zsum = (float*)(cnt + CC);      // CC
    unsigned* ctr = (unsigned*)(zsum + CC);

    hv_prep<<<PB, 256, 0, stream>>>(label, vp, ux, uy, dz,
                                    acc, hist, cnt, zsum, ctr);
    hv_vote<<<dim3(PB, QG), 256, 0, stream>>>(label, ux, uy, acc, hist);
    hv_gather<<<PB, 256, 0, stream>>>(label, ux, uy, dz, acc, hist,
                                      cnt, zsum, ctr,
                                      extents, poses, meta, out);
}